// Round 5
// baseline (158.392 us; speedup 1.0000x reference)
//
#include <hip/hip_runtime.h>

// ---------------------------------------------------------------------------
// MHA block: qkv = x@W_attn + b ; causal softmax((q k^T)/sqrt(C)) @ v ; @W_proj
// B=2 T=2048 C=1024 H=16 D=64.  bf16 MFMA, f32 accumulate.
// R5: barrier-free attention — zero LDS, K and V both loaded straight from
// L2 into per-lane register fragments (loop-ahead prefetch), 64-thread
// single-wave blocks (2048 of them, long-first, self-balancing).
// ---------------------------------------------------------------------------

typedef short bfrag __attribute__((ext_vector_type(8)));   // 8 bf16 bit-patterns
typedef float facc  __attribute__((ext_vector_type(4)));   // 16x16 MFMA C/D
typedef float f16v  __attribute__((ext_vector_type(16)));  // 32x32 MFMA C/D
typedef float f4v   __attribute__((ext_vector_type(4)));
typedef unsigned int u32x2 __attribute__((ext_vector_type(2)));
typedef unsigned int u32x4v __attribute__((ext_vector_type(4)));
typedef unsigned short u16;

#define MFMA16(a, b, c) __builtin_amdgcn_mfma_f32_16x16x32_bf16((a), (b), (c), 0, 0, 0)
#define MFMA32(a, b, c) __builtin_amdgcn_mfma_f32_32x32x16_bf16((a), (b), (c), 0, 0, 0)

__device__ __forceinline__ u16 f2bf(float f) {
  union { float f; unsigned u; } v; v.f = f;
  unsigned r = v.u + 0x7fffu + ((v.u >> 16) & 1u);   // round-to-nearest-even
  return (u16)(r >> 16);
}

__device__ __forceinline__ unsigned cvtpk(float lo, float hi) {
  unsigned r;
  asm("v_cvt_pk_bf16_f32 %0, %1, %2" : "=v"(r) : "v"(lo), "v"(hi));
  return r;
}

__device__ __forceinline__ void async_lds16(const void* g, void* l) {
  __builtin_amdgcn_global_load_lds(
      (const __attribute__((address_space(1))) unsigned char*)g,
      (__attribute__((address_space(3))) unsigned char*)l, 16, 0, 0);
}

// --------------------------- prep kernels ----------------------------------

__global__ void cast_bf16_kernel(const float* __restrict__ s, u16* __restrict__ d, int n) {
  int i = (blockIdx.x * blockDim.x + threadIdx.x) * 4;
  if (i >= n) return;
  f4v v = *reinterpret_cast<const f4v*>(s + i);
  u32x2 w;
  w[0] = (unsigned)f2bf(v[0]) | ((unsigned)f2bf(v[1]) << 16);
  w[1] = (unsigned)f2bf(v[2]) | ((unsigned)f2bf(v[3]) << 16);
  *reinterpret_cast<u32x2*>(d + i) = w;
}

// dst[n][k] = (bf16) src[k][n];  src is [K][N] f32 row-major
__global__ void transpose_cast_kernel(const float* __restrict__ src, u16* __restrict__ dst,
                                      int K, int N) {
  __shared__ float tile[32][33];
  int tx = threadIdx.x, ty = threadIdx.y;
  int n0 = blockIdx.x * 32, k0 = blockIdx.y * 32;
  for (int j = ty; j < 32; j += 8)
    tile[j][tx] = src[(size_t)(k0 + j) * N + (n0 + tx)];
  __syncthreads();
  for (int j = ty; j < 32; j += 8)
    dst[(size_t)(n0 + j) * K + (k0 + tx)] = f2bf(tile[tx][j]);
}

// --------------------------- GEMM (m97-structure) --------------------------

template <int EPI>
__global__ __launch_bounds__(256) void gemm_kernel(
    const u16* __restrict__ A, const u16* __restrict__ Bt,
    const float* __restrict__ bias, float* __restrict__ outf,
    u16* __restrict__ qb, u16* __restrict__ kb, u16* __restrict__ vb) {
  constexpr int KD = 1024;
  __shared__ u16 As[128 * 32];
  __shared__ u16 Bs[128 * 32];
  const int t = threadIdx.x;
  const int l = t & 63, w = t >> 6;
  const int wm = w >> 1, wn = w & 1;
  const int lg = l >> 4, lc = l & 15;
  const int m0 = blockIdx.y * 128, n0 = blockIdx.x * 128;
  facc acc[4][4] = {};
  const int srow = t >> 2, scol = (t & 3) * 8;      // staging: 16B per thread per call
  const u16* ga = A + (size_t)(m0 + srow) * KD + scol;
  const u16* gb = Bt + (size_t)(n0 + srow) * KD + scol;
  u16* la0 = As + t * 8;  u16* la1 = As + 2048 + t * 8;
  u16* lb0 = Bs + t * 8;  u16* lb1 = Bs + 2048 + t * 8;
  for (int kt = 0; kt < KD / 32; ++kt) {
    __syncthreads();
    async_lds16(ga + kt * 32, la0);
    async_lds16(ga + 64 * KD + kt * 32, la1);
    async_lds16(gb + kt * 32, lb0);
    async_lds16(gb + 64 * KD + kt * 32, lb1);
    __syncthreads();
    bfrag a[4], b[4];
#pragma unroll
    for (int mi = 0; mi < 4; ++mi)
      a[mi] = *reinterpret_cast<const bfrag*>(As + (wm * 64 + mi * 16 + lc) * 32 + lg * 8);
#pragma unroll
    for (int ni = 0; ni < 4; ++ni)
      b[ni] = *reinterpret_cast<const bfrag*>(Bs + (wn * 64 + ni * 16 + lc) * 32 + lg * 8);
#pragma unroll
    for (int mi = 0; mi < 4; ++mi)
#pragma unroll
      for (int ni = 0; ni < 4; ++ni)
        acc[mi][ni] = MFMA16(a[mi], b[ni], acc[mi][ni]);
  }
  // epilogue: C/D layout col = l&15, row = 4*(l>>4)+reg  (m89-verified)
#pragma unroll
  for (int mi = 0; mi < 4; ++mi) {
#pragma unroll
    for (int ni = 0; ni < 4; ++ni) {
#pragma unroll
      for (int r = 0; r < 4; ++r) {
        int gm = m0 + wm * 64 + mi * 16 + lg * 4 + r;
        int gn = n0 + wn * 64 + ni * 16 + lc;
        float val = acc[mi][ni][r] + bias[gn];
        if constexpr (EPI == 0) {
          int sec = gn >> 10, ci = gn & 1023;
          int h = ci >> 6, d = ci & 63;
          int b_ = gm >> 11, tq = gm & 2047;
          int bh = b_ * 16 + h;
          if (sec == 0) {
            // fold (1/sqrt(C)) * log2(e) into Q for exp2-domain softmax
            qb[((size_t)bh * 2048 + tq) * 64 + d] = f2bf(val * 0.045084439f);
          } else if (sec == 1) {
            kb[((size_t)bh * 2048 + tq) * 64 + d] = f2bf(val);
          } else {
            // V stored TRANSPOSED: [bh][d][t]
            vb[((size_t)bh * 64 + d) * 2048 + tq] = f2bf(val);
          }
        } else {
          outf[(size_t)gm * 1024 + gn] = val;
        }
      }
    }
  }
}

// --------------------------- flash attention -------------------------------
// Swapped-QK 32x32: S^T = mfma32(A=K, B=Q), lane owns q-col q0+(l&31);
// softmax in-register; P -> A-frag via cvt_pk + permlane32_swap.
// R5: ZERO LDS, ZERO BARRIERS.  One wave per block (64 threads), one 32-row
// q-chunk per wave.  K fragment loaded from L2 right after previous QK
// consumed it (~500cy ahead of use); V hand-rotated A/B one tile ahead.
// Grid 2048: bh = b&31 (XCD gets 4 heads = 2 MB K/V, L2-fit);
// chunk = 63-(b>>5) long-first for scheduler self-balancing.

__global__ __launch_bounds__(64, 2) void attn_kernel(
    const u16* __restrict__ Qb, const u16* __restrict__ Kb,
    const u16* __restrict__ Vtb, u16* __restrict__ attn) {
  constexpr int T = 2048;
  const int l = threadIdx.x & 63;
  const int c = l & 31, h = l >> 5;
  const int b = blockIdx.x;
  const int bh = b & 31;
  const int chunk = 63 - (b >> 5);     // 32-row q-chunk, long tiles first
  const int ntile = (chunk >> 1) + 1;  // KV tiles of 64
  const int q0 = chunk * 32;
  const size_t base = (size_t)bh * T * 64;
  const u16* Qp = Qb + base;
  const u16* Kp = Kb + base;
  const u16* Vp = Vtb + base;          // [d][T]

  // Q fragments (B-operand): qf[dt], elem j = Q[q0+c][16dt+8h+j]
  bfrag qf[4];
#pragma unroll
  for (int dt = 0; dt < 4; ++dt)
    qf[dt] = *reinterpret_cast<const bfrag*>(Qp + (size_t)(q0 + c) * 64 + dt * 16 + 8 * h);

  f16v o[2] = {};                      // [nt] output accum (32q x 64d)
  f16v s[2];                           // S^T scores
  float m_ = -1e30f, l_ = 0.f;

  // K A-fragment: kf[kt*4+dt] elem j = K[kvb+32kt+c][16dt+8h+j]
#define LOADK(kf, kvb_)                                                          \
  {                                                                              \
    _Pragma("unroll")                                                            \
    for (int kt = 0; kt < 2; ++kt)                                               \
      _Pragma("unroll")                                                          \
      for (int dt = 0; dt < 4; ++dt)                                             \
        kf[kt * 4 + dt] = *reinterpret_cast<const bfrag*>(                       \
            Kp + (size_t)((kvb_) + 32 * kt + c) * 64 + 16 * dt + 8 * h);         \
  }
  // V B-fragment: vf[nt*4+k2] elem j = V^T[32nt+c][kvb+16k2+8h+j]
#define LOADV(vf, kvb_)                                                          \
  {                                                                              \
    _Pragma("unroll")                                                            \
    for (int nt = 0; nt < 2; ++nt)                                               \
      _Pragma("unroll")                                                          \
      for (int k2 = 0; k2 < 4; ++k2)                                             \
        vf[nt * 4 + k2] = *reinterpret_cast<const bfrag*>(                       \
            Vp + (size_t)(32 * nt + c) * T + (kvb_) + 16 * k2 + 8 * h);          \
  }

  auto qk = [&](const bfrag kf[8]) {
    const f16v z = {};
    s[0] = z; s[1] = z;
    __builtin_amdgcn_s_setprio(1);
#pragma unroll
    for (int kt = 0; kt < 2; ++kt)
#pragma unroll
      for (int dt = 0; dt < 4; ++dt)
        s[kt] = MFMA32(kf[kt * 4 + dt], qf[dt], s[kt]);
    __builtin_amdgcn_s_setprio(0);
  };

  auto pv = [&](const bfrag pa[4], const bfrag vf[8]) {
    __builtin_amdgcn_s_setprio(1);
#pragma unroll
    for (int nt = 0; nt < 2; ++nt)
#pragma unroll
      for (int k2 = 0; k2 < 4; ++k2)
        o[nt] = MFMA32(pa[k2], vf[nt * 4 + k2], o[nt]);
    __builtin_amdgcn_s_setprio(0);
  };

  auto softmax_pa = [&](int it, bfrag pa[4]) {
    // causal mask (diagonal tile only)
    if (it == ntile - 1) {
      const int kvb = 64 * it;
      const int qq = q0 + c;
#pragma unroll
      for (int kt = 0; kt < 2; ++kt)
#pragma unroll
        for (int r = 0; r < 16; ++r) {
          const int kk = kvb + 32 * kt + (r & 3) + 8 * (r >> 2) + 4 * h;
          if (kk > qq) s[kt][r] = -1e30f;
        }
    }
    // max: 4-way tree
    float pms[4] = {-1e30f, -1e30f, -1e30f, -1e30f};
#pragma unroll
    for (int kt = 0; kt < 2; ++kt)
#pragma unroll
      for (int r = 0; r < 16; ++r) pms[r & 3] = fmaxf(pms[r & 3], s[kt][r]);
    float pm = fmaxf(fmaxf(pms[0], pms[1]), fmaxf(pms[2], pms[3]));
    pm = fmaxf(pm, __shfl_xor(pm, 32));
    if (!__all(pm <= m_ + 8.0f)) {       // T13 defer-max, THR=8
      const float mn = fmaxf(m_, pm);
      const float al = exp2f(m_ - mn);
      l_ *= al;
#pragma unroll
      for (int r = 0; r < 16; ++r) {
        const float ar = __shfl(al, (r & 3) + 8 * (r >> 2) + 4 * h);
        o[0][r] *= ar;
        o[1][r] *= ar;
      }
      m_ = mn;
    }
    // exp + sum (4-way tree)
    float ps[4] = {0.f, 0.f, 0.f, 0.f};
#pragma unroll
    for (int kt = 0; kt < 2; ++kt)
#pragma unroll
      for (int r = 0; r < 16; ++r) {
        const float e = exp2f(s[kt][r] - m_);
        s[kt][r] = e;
        ps[r & 3] += e;
      }
    float pss = (ps[0] + ps[1]) + (ps[2] + ps[3]);
    pss += __shfl_xor(pss, 32);
    l_ += pss;
    // P -> A-fragments: cvt_pk + permlane32_swap
#pragma unroll
    for (int kt = 0; kt < 2; ++kt)
#pragma unroll
      for (int sub = 0; sub < 2; ++sub) {
        const int bs = 8 * sub;
        unsigned x1 = cvtpk(s[kt][bs + 0], s[kt][bs + 1]);
        unsigned y1 = cvtpk(s[kt][bs + 4], s[kt][bs + 5]);
        asm volatile("v_permlane32_swap_b32 %0, %1" : "+v"(x1), "+v"(y1));
        unsigned x2 = cvtpk(s[kt][bs + 2], s[kt][bs + 3]);
        unsigned y2 = cvtpk(s[kt][bs + 6], s[kt][bs + 7]);
        asm volatile("v_permlane32_swap_b32 %0, %1" : "+v"(x2), "+v"(y2));
        union { u32x4v wv; bfrag f; } u;
        u.wv[0] = x1; u.wv[1] = x2; u.wv[2] = y1; u.wv[3] = y2;
        pa[2 * kt + sub] = u.f;
      }
  };

  bfrag kf[8], vfA[8], vfB[8], pa[4];

  // ---- prologue ----
  LOADK(kf, 0);
  LOADV(vfA, 0);

  // ---- main loop: qk(cur) -> prefetch K(next) -> softmax -> prefetch
  //      V(next, other buf) -> pv(cur).  No barriers; latency hidden by
  //      loop distance + the co-resident waves on this SIMD. ----
  int it = 0;
  bool useA = true;
  while (true) {
    qk(kf);                                   // consumes K(it)
    if (it + 1 < ntile) LOADK(kf, 64 * (it + 1));
    softmax_pa(it, pa);
    if (useA) {
      if (it + 1 < ntile) LOADV(vfB, 64 * (it + 1));
      pv(pa, vfA);                            // consumes V(it)
    } else {
      if (it + 1 < ntile) LOADV(vfA, 64 * (it + 1));
      pv(pa, vfB);
    }
    useA = !useA;
    if (++it >= ntile) break;
  }

  // ---- epilogue: O / l, write [b][t][h*64+d] bf16 ----
  const int b_ = bh >> 4, hd = bh & 15;
  const float linv = 1.0f / l_;
#pragma unroll
  for (int r = 0; r < 16; ++r) {
    const int row = (r & 3) + 8 * (r >> 2) + 4 * h;
    const float lr = __shfl(linv, row);
    const int tq = q0 + row;
#pragma unroll
    for (int nt = 0; nt < 2; ++nt) {
      const int col = hd * 64 + 32 * nt + c;
      attn[((size_t)(b_ * T + tq)) * 1024 + col] = f2bf(o[nt][r] * lr);
    }
  }
#undef LOADK
#undef LOADV
}

// --------------------------- launcher --------------------------------------

extern "C" void kernel_launch(void* const* d_in, const int* in_sizes, int n_in,
                              void* d_out, int out_size, void* d_ws, size_t ws_size,
                              hipStream_t stream) {
  const float* x      = (const float*)d_in[0];
  const float* W_attn = (const float*)d_in[1];
  const float* b_attn = (const float*)d_in[2];
  const float* W_proj = (const float*)d_in[3];
  const float* b_proj = (const float*)d_in[4];
  float* out = (float*)d_out;
  char* ws = (char*)d_ws;
  // ws layout (48 MiB total)
  u16* xb   = (u16*)(ws);                       // [4096][1024] bf16   8 MiB
  u16* Wat  = (u16*)(ws + (8u  << 20));         // [3072][1024] bf16   6 MiB
  u16* Wpt  = (u16*)(ws + (14u << 20));         // [1024][1024] bf16   2 MiB
  u16* Qb   = (u16*)(ws + (16u << 20));         // [bh][t][d] bf16     8 MiB
  u16* Kb   = (u16*)(ws + (24u << 20));         // [bh][t][d]          8 MiB
  u16* Vtb  = (u16*)(ws + (32u << 20));         // [bh][d][t] (V^T)    8 MiB
  u16* attn = (u16*)(ws + (40u << 20));         // [4096][1024] bf16   8 MiB

  cast_bf16_kernel<<<4096, 256, 0, stream>>>(x, xb, 4096 * 1024);
  transpose_cast_kernel<<<dim3(96, 32), dim3(32, 8), 0, stream>>>(W_attn, Wat, 1024, 3072);
  transpose_cast_kernel<<<dim3(32, 32), dim3(32, 8), 0, stream>>>(W_proj, Wpt, 1024, 1024);
  gemm_kernel<0><<<dim3(24, 32), 256, 0, stream>>>(xb, Wat, b_attn, nullptr, Qb, Kb, Vtb);
  attn_kernel<<<2048, 64, 0, stream>>>(Qb, Kb, Vtb, attn);
  gemm_kernel<1><<<dim3(8, 32), 256, 0, stream>>>(attn, Wpt, b_proj, out, nullptr, nullptr, nullptr);
}

// Round 8
// 138.753 us; speedup vs baseline: 1.1415x; 1.1415x over previous
//
#include <hip/hip_runtime.h>

// ---------------------------------------------------------------------------
// MHA block: qkv = x@W_attn + b ; causal softmax((q k^T)/sqrt(C)) @ v ; @W_proj
// B=2 T=2048 C=1024 H=16 D=64.  bf16 MFMA, f32 accumulate.
// R8: KV-split attention, barrier-verified implementation.  Block = 2 waves
// sharing one 32-row q-chunk; wave w owns kv tiles w, w+2, ... with private
// dbuf K-LDS; one __syncthreads per round (2 tiles); V direct->regs (A/B
// rotated); shfl_xor reductions (HW-proven path); end merge of (m,l,O).
// ---------------------------------------------------------------------------

typedef short bfrag __attribute__((ext_vector_type(8)));   // 8 bf16 bit-patterns
typedef float facc  __attribute__((ext_vector_type(4)));   // 16x16 MFMA C/D
typedef float f16v  __attribute__((ext_vector_type(16)));  // 32x32 MFMA C/D
typedef float f4v   __attribute__((ext_vector_type(4)));
typedef unsigned int u32x2 __attribute__((ext_vector_type(2)));
typedef unsigned int u32x4v __attribute__((ext_vector_type(4)));
typedef unsigned short u16;

#define MFMA16(a, b, c) __builtin_amdgcn_mfma_f32_16x16x32_bf16((a), (b), (c), 0, 0, 0)
#define MFMA32(a, b, c) __builtin_amdgcn_mfma_f32_32x32x16_bf16((a), (b), (c), 0, 0, 0)

__device__ __forceinline__ u16 f2bf(float f) {
  union { float f; unsigned u; } v; v.f = f;
  unsigned r = v.u + 0x7fffu + ((v.u >> 16) & 1u);   // round-to-nearest-even
  return (u16)(r >> 16);
}

__device__ __forceinline__ unsigned cvtpk(float lo, float hi) {
  unsigned r;
  asm("v_cvt_pk_bf16_f32 %0, %1, %2" : "=v"(r) : "v"(lo), "v"(hi));
  return r;
}

__device__ __forceinline__ void async_lds16(const void* g, void* l) {
  __builtin_amdgcn_global_load_lds(
      (const __attribute__((address_space(1))) unsigned char*)g,
      (__attribute__((address_space(3))) unsigned char*)l, 16, 0, 0);
}

// --------------------------- prep kernels ----------------------------------

__global__ void cast_bf16_kernel(const float* __restrict__ s, u16* __restrict__ d, int n) {
  int i = (blockIdx.x * blockDim.x + threadIdx.x) * 4;
  if (i >= n) return;
  f4v v = *reinterpret_cast<const f4v*>(s + i);
  u32x2 w;
  w[0] = (unsigned)f2bf(v[0]) | ((unsigned)f2bf(v[1]) << 16);
  w[1] = (unsigned)f2bf(v[2]) | ((unsigned)f2bf(v[3]) << 16);
  *reinterpret_cast<u32x2*>(d + i) = w;
}

// dst[n][k] = (bf16) src[k][n];  src is [K][N] f32 row-major
__global__ void transpose_cast_kernel(const float* __restrict__ src, u16* __restrict__ dst,
                                      int K, int N) {
  __shared__ float tile[32][33];
  int tx = threadIdx.x, ty = threadIdx.y;
  int n0 = blockIdx.x * 32, k0 = blockIdx.y * 32;
  for (int j = ty; j < 32; j += 8)
    tile[j][tx] = src[(size_t)(k0 + j) * N + (n0 + tx)];
  __syncthreads();
  for (int j = ty; j < 32; j += 8)
    dst[(size_t)(n0 + j) * K + (k0 + tx)] = f2bf(tile[tx][j]);
}

// --------------------------- GEMM (m97-structure) --------------------------

template <int EPI>
__global__ __launch_bounds__(256) void gemm_kernel(
    const u16* __restrict__ A, const u16* __restrict__ Bt,
    const float* __restrict__ bias, float* __restrict__ outf,
    u16* __restrict__ qb, u16* __restrict__ kb, u16* __restrict__ vb) {
  constexpr int KD = 1024;
  __shared__ u16 As[128 * 32];
  __shared__ u16 Bs[128 * 32];
  const int t = threadIdx.x;
  const int l = t & 63, w = t >> 6;
  const int wm = w >> 1, wn = w & 1;
  const int lg = l >> 4, lc = l & 15;
  const int m0 = blockIdx.y * 128, n0 = blockIdx.x * 128;
  facc acc[4][4] = {};
  const int srow = t >> 2, scol = (t & 3) * 8;      // staging: 16B per thread per call
  const u16* ga = A + (size_t)(m0 + srow) * KD + scol;
  const u16* gb = Bt + (size_t)(n0 + srow) * KD + scol;
  u16* la0 = As + t * 8;  u16* la1 = As + 2048 + t * 8;
  u16* lb0 = Bs + t * 8;  u16* lb1 = Bs + 2048 + t * 8;
  for (int kt = 0; kt < KD / 32; ++kt) {
    __syncthreads();
    async_lds16(ga + kt * 32, la0);
    async_lds16(ga + 64 * KD + kt * 32, la1);
    async_lds16(gb + kt * 32, lb0);
    async_lds16(gb + 64 * KD + kt * 32, lb1);
    __syncthreads();
    bfrag a[4], b[4];
#pragma unroll
    for (int mi = 0; mi < 4; ++mi)
      a[mi] = *reinterpret_cast<const bfrag*>(As + (wm * 64 + mi * 16 + lc) * 32 + lg * 8);
#pragma unroll
    for (int ni = 0; ni < 4; ++ni)
      b[ni] = *reinterpret_cast<const bfrag*>(Bs + (wn * 64 + ni * 16 + lc) * 32 + lg * 8);
#pragma unroll
    for (int mi = 0; mi < 4; ++mi)
#pragma unroll
      for (int ni = 0; ni < 4; ++ni)
        acc[mi][ni] = MFMA16(a[mi], b[ni], acc[mi][ni]);
  }
  // epilogue: C/D layout col = l&15, row = 4*(l>>4)+reg  (m89-verified)
#pragma unroll
  for (int mi = 0; mi < 4; ++mi) {
#pragma unroll
    for (int ni = 0; ni < 4; ++ni) {
#pragma unroll
      for (int r = 0; r < 4; ++r) {
        int gm = m0 + wm * 64 + mi * 16 + lg * 4 + r;
        int gn = n0 + wn * 64 + ni * 16 + lc;
        float val = acc[mi][ni][r] + bias[gn];
        if constexpr (EPI == 0) {
          int sec = gn >> 10, ci = gn & 1023;
          int h = ci >> 6, d = ci & 63;
          int b_ = gm >> 11, tq = gm & 2047;
          int bh = b_ * 16 + h;
          if (sec == 0) {
            // fold (1/sqrt(C)) * log2(e) into Q for exp2-domain softmax
            qb[((size_t)bh * 2048 + tq) * 64 + d] = f2bf(val * 0.045084439f);
          } else if (sec == 1) {
            kb[((size_t)bh * 2048 + tq) * 64 + d] = f2bf(val);
          } else {
            // V stored TRANSPOSED: [bh][d][t]
            vb[((size_t)bh * 64 + d) * 2048 + tq] = f2bf(val);
          }
        } else {
          outf[(size_t)gm * 1024 + gn] = val;
        }
      }
    }
  }
}

// --------------------------- flash attention -------------------------------
// Swapped-QK 32x32, in-reg softmax (lane owns q-row q0+(l&31)); P -> A-frag
// via cvt_pk + permlane32_swap (R2-proven).  KV-split: wave w owns tiles
// w, w+2, ...; private dbuf K-LDS [parity][wave]; one __syncthreads per
// round (implicit vmcnt/lgkm drain = proven sync).  V from L2 into regs,
// rotated A/B one round ahead.  End: merge (m,l,O) via LDS scratch.
// Grid 2048 = 32 bh x 64 chunks; bh = b&31, chunk long-first.

__global__ __launch_bounds__(128, 2) void attn_kernel(
    const u16* __restrict__ Qb, const u16* __restrict__ Kb,
    const u16* __restrict__ Vtb, u16* __restrict__ attn) {
  constexpr int T = 2048;
  __shared__ u16 Ks[2][2][64 * 64];    // [buf parity][wave]
  const int t = threadIdx.x;
  const int l = t & 63, w = t >> 6;
  const int c = l & 31, h = l >> 5;
  const int b = blockIdx.x;
  const int bh = b & 31;
  const int chunk = 63 - (b >> 5);     // 32-row q-chunk, long first
  const int ntile = (chunk >> 1) + 1;  // KV tiles of 64
  const int nrounds = (ntile + 1) >> 1;
  const int q0 = chunk * 32;
  const size_t base = (size_t)bh * T * 64;
  const u16* Qp = Qb + base;
  const u16* Kp = Kb + base;
  const u16* Vp = Vtb + base;          // [d][T]

  // Q fragments (B-operand): qf[dt], elem j = Q[q0+c][16dt+8h+j]
  bfrag qf[4];
#pragma unroll
  for (int dt = 0; dt < 4; ++dt)
    qf[dt] = *reinterpret_cast<const bfrag*>(Qp + (size_t)(q0 + c) * 64 + dt * 16 + 8 * h);

  f16v o[2] = {};                      // O accum: row=q(rmap), col=d(32nt+c)
  f16v s[2];
  float m_ = -1e30f, l_ = 0.f;

  // K staging (per wave, 8 calls x 1KB): LDS linear, source XOR-swizzled
  const int srow0 = l >> 3;                       // + 8j
  const int sw8   = ((l & 7) ^ (l >> 3)) * 8;     // swizzled source chunk
  u16* kb0 = &Ks[0][w][0];
  u16* kb1 = &Ks[1][w][0];

#define STAGE_K(dst, kvb_)                                                       \
  {                                                                              \
    _Pragma("unroll")                                                            \
    for (int j = 0; j < 8; ++j)                                                  \
      async_lds16(Kp + (size_t)((kvb_) + srow0 + 8 * j) * 64 + sw8,              \
                  (dst) + 512 * j);                                              \
  }
  // V B-fragment: vf[nt*4+k2] elem j = V^T[32nt+c][kvb+16k2+8h+j]
#define LOADV(vf, kvb_)                                                          \
  {                                                                              \
    _Pragma("unroll")                                                            \
    for (int nt = 0; nt < 2; ++nt)                                               \
      _Pragma("unroll")                                                          \
      for (int k2 = 0; k2 < 4; ++k2)                                             \
        vf[nt * 4 + k2] = *reinterpret_cast<const bfrag*>(                       \
            Vp + (size_t)(32 * nt + c) * T + (kvb_) + 16 * k2 + 8 * h);          \
  }

  auto qk = [&](const u16* ks) {
    const f16v z = {};
    s[0] = z; s[1] = z;
    __builtin_amdgcn_s_setprio(1);
#pragma unroll
    for (int kt = 0; kt < 2; ++kt)
#pragma unroll
      for (int dt = 0; dt < 4; ++dt) {
        const bfrag a = *reinterpret_cast<const bfrag*>(
            ks + (32 * kt + c) * 64 + (((2 * dt + h) ^ (c & 7)) * 8));
        s[kt] = MFMA32(a, qf[dt], s[kt]);
      }
    __builtin_amdgcn_s_setprio(0);
  };

  auto pv = [&](const bfrag pa[4], const bfrag vf[8]) {
    __builtin_amdgcn_s_setprio(1);
#pragma unroll
    for (int nt = 0; nt < 2; ++nt)
#pragma unroll
      for (int k2 = 0; k2 < 4; ++k2)
        o[nt] = MFMA32(pa[k2], vf[nt * 4 + k2], o[nt]);
    __builtin_amdgcn_s_setprio(0);
  };

  auto softmax_pa = [&](int it, bfrag pa[4]) {
    // causal mask (diagonal tile only)
    if (it == ntile - 1) {
      const int kvb = 64 * it;
      const int qq = q0 + c;
#pragma unroll
      for (int kt = 0; kt < 2; ++kt)
#pragma unroll
        for (int r = 0; r < 16; ++r) {
          const int kk = kvb + 32 * kt + (r & 3) + 8 * (r >> 2) + 4 * h;
          if (kk > qq) s[kt][r] = -1e30f;
        }
    }
    // max: 4-way tree + cross-32 shfl (HW-proven)
    float pms[4] = {-1e30f, -1e30f, -1e30f, -1e30f};
#pragma unroll
    for (int kt = 0; kt < 2; ++kt)
#pragma unroll
      for (int r = 0; r < 16; ++r) pms[r & 3] = fmaxf(pms[r & 3], s[kt][r]);
    float pm = fmaxf(fmaxf(pms[0], pms[1]), fmaxf(pms[2], pms[3]));
    pm = fmaxf(pm, __shfl_xor(pm, 32));
    if (!__all(pm <= m_ + 8.0f)) {       // T13 defer-max, THR=8
      const float mn = fmaxf(m_, pm);
      const float al = exp2f(m_ - mn);
      l_ *= al;
#pragma unroll
      for (int r = 0; r < 16; ++r) {
        const float ar = __shfl(al, (r & 3) + 8 * (r >> 2) + 4 * h);
        o[0][r] *= ar;
        o[1][r] *= ar;
      }
      m_ = mn;
    }
    // exp + sum (4-way tree) + cross-32 shfl
    float ps[4] = {0.f, 0.f, 0.f, 0.f};
#pragma unroll
    for (int kt = 0; kt < 2; ++kt)
#pragma unroll
      for (int r = 0; r < 16; ++r) {
        const float e = exp2f(s[kt][r] - m_);
        s[kt][r] = e;
        ps[r & 3] += e;
      }
    float pss = (ps[0] + ps[1]) + (ps[2] + ps[3]);
    pss += __shfl_xor(pss, 32);
    l_ += pss;
    // P -> A-fragments: cvt_pk + permlane32_swap (R2-proven)
#pragma unroll
    for (int kt = 0; kt < 2; ++kt)
#pragma unroll
      for (int sub = 0; sub < 2; ++sub) {
        const int bs = 8 * sub;
        unsigned x1 = cvtpk(s[kt][bs + 0], s[kt][bs + 1]);
        unsigned y1 = cvtpk(s[kt][bs + 4], s[kt][bs + 5]);
        asm volatile("v_permlane32_swap_b32 %0, %1" : "+v"(x1), "+v"(y1));
        unsigned x2 = cvtpk(s[kt][bs + 2], s[kt][bs + 3]);
        unsigned y2 = cvtpk(s[kt][bs + 6], s[kt][bs + 7]);
        asm volatile("v_permlane32_swap_b32 %0, %1" : "+v"(x2), "+v"(y2));
        union { u32x4v wv; bfrag f; } u;
        u.wv[0] = x1; u.wv[1] = x2; u.wv[2] = y1; u.wv[3] = y2;
        pa[2 * kt + sub] = u.f;
      }
  };

  // ---- rounds: wave w computes tile 2r+w; stages tile 2(r+1)+w ----
  bfrag vfA[8], vfB[8], pa[4];
  if (w < ntile) { STAGE_K(kb0, 64 * w); LOADV(vfA, 64 * w); }
  __syncthreads();                      // round-0 K landed (barrier drains vmcnt)
  for (int r = 0; r < nrounds; ++r) {
    const int it = 2 * r + w;
    const int itn = it + 2;
    if (itn < ntile) {
      if (r & 1) { STAGE_K(kb0, 64 * itn); LOADV(vfA, 64 * itn); }
      else       { STAGE_K(kb1, 64 * itn); LOADV(vfB, 64 * itn); }
    }
    if (it < ntile) {
      qk((r & 1) ? kb1 : kb0);
      softmax_pa(it, pa);
      pv(pa, (r & 1) ? vfB : vfA);
    }
    __syncthreads();                    // next-round K landed; all quiesced
  }

  // ---- merge the two waves' partials (no VMEM in flight past last barrier) ----
  float* Fo = (float*)&Ks[0][0][0];    // [64 dcol][33] padded + m + l
  float* Fm = Fo + 64 * 33;
  float* Fl = Fm + 32;
  if (w == 1) {
#pragma unroll
    for (int nt = 0; nt < 2; ++nt)
#pragma unroll
      for (int r = 0; r < 16; ++r) {
        const int row = (r & 3) + 8 * (r >> 2) + 4 * h;
        Fo[(nt * 32 + c) * 33 + row] = o[nt][r];
      }
    if (h == 0) { Fm[c] = m_; Fl[c] = l_; }
  }
  __syncthreads();
  if (w == 0) {
    const float m1v = Fm[c], l1v = Fl[c];
    const float mm = fmaxf(m_, m1v);
    const float a0 = exp2f(m_ - mm), a1 = exp2f(m1v - mm);
    const float linv = 1.0f / (a0 * l_ + a1 * l1v);
    const int b_ = bh >> 4, hd = bh & 15;
#pragma unroll
    for (int r = 0; r < 16; ++r) {
      const int row = (r & 3) + 8 * (r >> 2) + 4 * h;
      const float a0r = __shfl(a0, row);
      const float a1r = __shfl(a1, row);
      const float lr = __shfl(linv, row);
      const int tq = q0 + row;
#pragma unroll
      for (int nt = 0; nt < 2; ++nt) {
        const float o1 = Fo[(nt * 32 + c) * 33 + row];
        attn[((size_t)(b_ * T + tq)) * 1024 + hd * 64 + 32 * nt + c] =
            f2bf((a0r * o[nt][r] + a1r * o1) * lr);
      }
    }
  }
#undef STAGE_K
#undef LOADV
}

// --------------------------- launcher --------------------------------------

extern "C" void kernel_launch(void* const* d_in, const int* in_sizes, int n_in,
                              void* d_out, int out_size, void* d_ws, size_t ws_size,
                              hipStream_t stream) {
  const float* x      = (const float*)d_in[0];
  const float* W_attn = (const float*)d_in[1];
  const float* b_attn = (const float*)d_in[2];
  const float* W_proj = (const float*)d_in[3];
  const float* b_proj = (const float*)d_in[4];
  float* out = (float*)d_out;
  char* ws = (char*)d_ws;
  // ws layout (48 MiB total)
  u16* xb   = (u16*)(ws);                       // [4096][1024] bf16   8 MiB
  u16* Wat  = (u16*)(ws + (8u  << 20));         // [3072][1024] bf16   6 MiB
  u16* Wpt  = (u16*)(ws + (14u << 20));         // [1024][1024] bf16   2 MiB
  u16* Qb   = (u16*)(ws + (16u << 20));         // [bh][t][d] bf16     8 MiB
  u16* Kb   = (u16*)(ws + (24u << 20));         // [bh][t][d]          8 MiB
  u16* Vtb  = (u16*)(ws + (32u << 20));         // [bh][d][t] (V^T)    8 MiB
  u16* attn = (u16*)(ws + (40u << 20));         // [4096][1024] bf16   8 MiB

  cast_bf16_kernel<<<4096, 256, 0, stream>>>(x, xb, 4096 * 1024);
  transpose_cast_kernel<<<dim3(96, 32), dim3(32, 8), 0, stream>>>(W_attn, Wat, 1024, 3072);
  transpose_cast_kernel<<<dim3(32, 32), dim3(32, 8), 0, stream>>>(W_proj, Wpt, 1024, 1024);
  gemm_kernel<0><<<dim3(24, 32), 256, 0, stream>>>(xb, Wat, b_attn, nullptr, Qb, Kb, Vtb);
  attn_kernel<<<2048, 128, 0, stream>>>(Qb, Kb, Vtb, attn);
  gemm_kernel<1><<<dim3(8, 32), 256, 0, stream>>>(attn, Wpt, b_proj, out, nullptr, nullptr, nullptr);
}